// Round 15
// baseline (2381.522 us; speedup 1.0000x reference)
//
#include <hip/hip_runtime.h>
#include <math.h>

#define MIN_SWEEPS 6
#define MAX_SWEEPS 9
#define EPSV 1e-3
#define MAXEIG 1000.0

// ONE 64-lane wave per 64x64 symmetric matrix. ONE-SIDED Jacobi in registers,
// zero barriers in the main loop (see r14 notes: B = A + 0.5*||A||_F * I is
// PSD; lane j owns column w_j as 64 NAMED registers; XOR tournament pairing
// via ds_bpermute; both partners compute bitwise-identical (c,s)).
// Round-15 fixes (r14: occupancy 20% LDS-capped, 64-deep serial Gram chain):
//  - g accumulated in 8 static-indexed partials + pairwise tree: round
//    critical path ~256 -> ~45 cyc. fp64 Rayleigh inner dot: 4 partials.
//  - epilogue LDS halved to 32 rows (8.3 KB): two passes over eigenvector
//    halves (dump -> Rayleigh -> scale -> reconstruct-accumulate); pass 1
//    accumulates into om with += (deterministic: pass 0 overwrites first).
//    9 -> ~16 waves/CU. VGPR must stay <= 128 (4 waves/SIMD step).

#define REP64(X) \
  X(0) X(1) X(2) X(3) X(4) X(5) X(6) X(7) \
  X(8) X(9) X(10) X(11) X(12) X(13) X(14) X(15) \
  X(16) X(17) X(18) X(19) X(20) X(21) X(22) X(23) \
  X(24) X(25) X(26) X(27) X(28) X(29) X(30) X(31) \
  X(32) X(33) X(34) X(35) X(36) X(37) X(38) X(39) \
  X(40) X(41) X(42) X(43) X(44) X(45) X(46) X(47) \
  X(48) X(49) X(50) X(51) X(52) X(53) X(54) X(55) \
  X(56) X(57) X(58) X(59) X(60) X(61) X(62) X(63)

#define REP32(X) \
  X(0) X(1) X(2) X(3) X(4) X(5) X(6) X(7) \
  X(8) X(9) X(10) X(11) X(12) X(13) X(14) X(15) \
  X(16) X(17) X(18) X(19) X(20) X(21) X(22) X(23) \
  X(24) X(25) X(26) X(27) X(28) X(29) X(30) X(31)

__global__ __launch_bounds__(64)
void spd_log_kernel(const float* __restrict__ x, float* __restrict__ out) {
    __shared__ float vlds[32 * 65];   // epilogue only: 32 eigvec rows, pitch 65

    const int lane = (int)threadIdx.x;
    const int hb   = lane >> 5;       // which eigvec half this lane belongs to
    const int rl   = lane & 31;       // my row in the half-buffer
    const size_t mat = blockIdx.x;
    const float* __restrict__ xm = x + mat * (size_t)4096;
    float* __restrict__ om = out + mat * (size_t)4096;

#define DECLW(i) float w##i;
    REP64(DECLW)
#define DECLQ(i) float q##i;
    REP64(DECLQ)

    // load my column of A (coalesced per element index)
#define LOADW(i) w##i = xm[(i) * 64 + lane];
    REP64(LOADW)

    // gamma = 0.5 * ||A||_F
    float ff = 0.0f;
#define ACCF(i) ff = fmaf(w##i, w##i, ff);
    REP64(ACCF)
#pragma unroll
    for (int o = 32; o > 0; o >>= 1) ff += __shfl_xor(ff, o);
    const float gamma = 0.5f * sqrtf(ff);

    // B = A + gamma*I
#define SHIFTW(i) w##i += ((i) == lane) ? gamma : 0.0f;
    REP64(SHIFTW)

    float n = 0.0f;
#define ACCN(i) n = fmaf(w##i, w##i, n);
    REP64(ACCN)

    // ---------------- one-sided Jacobi sweeps (no barriers) ----------------
    for (int sweep = 0; sweep < MAX_SWEEPS; ++sweep) {
        n = 0.0f;                      // fresh norm kills recurrence drift
        REP64(ACCN)
        float S = n;
#pragma unroll
        for (int o = 32; o > 0; o >>= 1) S += __shfl_xor(S, o);
        float off2 = 0.0f;

        for (int m = 1; m < 64; ++m) {
            const int pidx = ((lane ^ m) << 2);
#define FETCH(i) q##i = __int_as_float(__builtin_amdgcn_ds_bpermute(pidx, __float_as_int(w##i)));
            REP64(FETCH)
            // Gram cross-dot in 8 static-indexed partials (short dep chains)
            float gp[8] = {0.f, 0.f, 0.f, 0.f, 0.f, 0.f, 0.f, 0.f};
#define ACCG(i) gp[(i) & 7] = fmaf(w##i, q##i, gp[(i) & 7]);
            REP64(ACCG)
            const float g = ((gp[0] + gp[1]) + (gp[2] + gp[3])) +
                            ((gp[4] + gp[5]) + (gp[6] + gp[7]));
            off2 = fmaf(g, g, off2);
            const float nq = __int_as_float(__builtin_amdgcn_ds_bpermute(pidx, __float_as_int(n)));
            const bool isp = lane < (lane ^ m);
            const float na = isp ? n : nq;
            const float nb = isp ? nq : n;
            const float tau = (nb - na) * (0.5f * __builtin_amdgcn_rcpf(g));
            const float at  = fabsf(tau);
            float t = __builtin_amdgcn_rcpf(at + __builtin_amdgcn_sqrtf(fmaf(at, at, 1.0f)));
            t = copysignf(t, tau);
            float c = __builtin_amdgcn_rsqf(fmaf(t, t, 1.0f));
            float s = t * c;
            const bool tiny = !(fabsf(g) > 1e-28f);   // exact-0 / NaN guard
            c = tiny ? 1.0f : c;
            s = tiny ? 0.0f : s;
            const float tg = tiny ? 0.0f : t * g;
            const float se = isp ? -s : s;
#define ROT(i) w##i = fmaf(se, q##i, c * w##i);
            REP64(ROT)
            n += isp ? -tg : tg;
        }
#pragma unroll
        for (int o = 32; o > 0; o >>= 1) off2 += __shfl_xor(off2, o);
        if (sweep >= MIN_SWEEPS - 1 && off2 < 1e-13f * S * S) break;
    }

    // ---------------- epilogue (two passes over eigvec halves) -------------
    n = 0.0f;
    REP64(ACCN)
    const float rn = __builtin_amdgcn_rsqf(n);
#define NRM(i) w##i *= rn;
    REP64(NRM)

    float f = 0.0f;   // my log-eigenvalue (set during my half's pass)

#pragma unroll
    for (int P = 0; P < 2; ++P) {
        __syncthreads();   // pass-1: everyone done reading previous half
        if (hb == P) {
            // dump my eigenvector into row rl (banks (rl+i)%32: unique/lane)
#define DUMP(i) vlds[rl * 65 + (i)] = w##i;
            REP64(DUMP)
        }
        __syncthreads();

        if (hb == P) {
            // fp64 Rayleigh vs ORIGINAL A: lambda = v^T A v (||v||=1).
            // inner dot in 4 static-indexed f64 partials.
            double acc = 0.0;
            for (int r = 0; r < 64; ++r) {
                double ip[4] = {0.0, 0.0, 0.0, 0.0};
#define RAYI(i) ip[(i) >> 4] = fma((double)xm[r * 64 + (i)], (double)w##i, ip[(i) >> 4]);
                REP64(RAYI)
                const double inner = (ip[0] + ip[1]) + (ip[2] + ip[3]);
                acc = fma((double)vlds[rl * 65 + r], inner, acc);
            }
            double lam = fmin(fmax(acc, (double)EPSV), (double)MAXEIG);
            f = (float)log(lam);
        }

        // q_i <- f_j * v_j[lane] for j = 32P+i (transpose read, 2-way free;
        // f_j via v_readlane with uniform SGPR index)
#define G2(i) q##i = __uint_as_float(__builtin_amdgcn_readlane(__float_as_uint(f), 32 * P + (i))) * vlds[(i) * 65 + lane];
        REP32(G2)

        // Out[r][lane] (+)= sum_{i<32} v_j[r] * q_i ; v_j[r] broadcast read
        for (int r = 0; r < 64; ++r) {
            float a = 0.0f;
#define RECI(i) a = fmaf(vlds[(i) * 65 + r], q##i, a);
            REP32(RECI)
            if (P == 0) om[r * 64 + lane] = a;
            else        om[r * 64 + lane] += a;
        }
    }
}

extern "C" void kernel_launch(void* const* d_in, const int* in_sizes, int n_in,
                              void* d_out, int out_size, void* d_ws, size_t ws_size,
                              hipStream_t stream) {
    const float* x = (const float*)d_in[0];
    float* out = (float*)d_out;
    const int nmat = in_sizes[0] / 4096;
    spd_log_kernel<<<dim3(nmat), dim3(64), 0, stream>>>(x, out);
}

// Round 16
// 1709.917 us; speedup vs baseline: 1.3928x; 1.3928x over previous
//
#include <hip/hip_runtime.h>
#include <math.h>

#define MIN_SWEEPS 6
#define MAX_SWEEPS 9
#define EPSV 1e-3
#define MAXEIG 1000.0
#define EP 68   // epilogue LDS pitch: rows 16B-aligned (float4 broadcast reads);
                // transpose read (4i+lane)%32 conflict-free; dump 8-way but 1x/matrix

// ONE 64-lane wave per 64x64 symmetric matrix. ONE-SIDED Jacobi in registers.
// B = A + 0.5*||A||_F*I (PSD for this data class); lane j owns column w_j as
// 64 NAMED registers; XOR tournament (partner lane^m) via ds_bpermute; both
// partners compute bitwise-identical (c,s).
// Roofline (r14 fit): main loop is LDS-pipe-bound at ~5.5cyc/wave-bpermute.
// r14 issued 129 bpermutes/round (compiler refetched q for the rotation,
// VGPR 84). r16: keep all 64 q LIVE -> 65 ops/round (the information floor),
// VGPR ~150 under __launch_bounds__(64,2) cap 256. r15's failure modes fixed:
// scratch spills (WRITE_SIZE +25MB) and exec-masked double-issue epilogue ->
// single-pass full-wave epilogue (r14's), float4 broadcast reconstruction.

#define REP64(X) \
  X(0) X(1) X(2) X(3) X(4) X(5) X(6) X(7) \
  X(8) X(9) X(10) X(11) X(12) X(13) X(14) X(15) \
  X(16) X(17) X(18) X(19) X(20) X(21) X(22) X(23) \
  X(24) X(25) X(26) X(27) X(28) X(29) X(30) X(31) \
  X(32) X(33) X(34) X(35) X(36) X(37) X(38) X(39) \
  X(40) X(41) X(42) X(43) X(44) X(45) X(46) X(47) \
  X(48) X(49) X(50) X(51) X(52) X(53) X(54) X(55) \
  X(56) X(57) X(58) X(59) X(60) X(61) X(62) X(63)

__global__ __launch_bounds__(64, 2)
void spd_log_kernel(const float* __restrict__ x, float* __restrict__ out) {
    __shared__ float vlds[64 * EP];   // 17.4 KB, epilogue only

    const int lane = (int)threadIdx.x;
    const size_t mat = blockIdx.x;
    const float* __restrict__ xm = x + mat * (size_t)4096;
    float* __restrict__ om = out + mat * (size_t)4096;

#define DECLW(i) float w##i;
    REP64(DECLW)
#define DECLQ(i) float q##i;
    REP64(DECLQ)

    // load my column of A
#define LOADW(i) w##i = xm[(i) * 64 + lane];
    REP64(LOADW)

    // gamma = 0.5 * ||A||_F
    float ff = 0.0f;
#define ACCF(i) ff = fmaf(w##i, w##i, ff);
    REP64(ACCF)
#pragma unroll
    for (int o = 32; o > 0; o >>= 1) ff += __shfl_xor(ff, o);
    const float gamma = 0.5f * sqrtf(ff);

    // B = A + gamma*I
#define SHIFTW(i) w##i += ((i) == lane) ? gamma : 0.0f;
    REP64(SHIFTW)

    float n = 0.0f;
#define ACCN(i) n = fmaf(w##i, w##i, n);
    REP64(ACCN)

    // ---------------- one-sided Jacobi sweeps (no barriers) ----------------
    for (int sweep = 0; sweep < MAX_SWEEPS; ++sweep) {
        n = 0.0f;                      // fresh norm kills recurrence drift
        REP64(ACCN)
        float S = n;
#pragma unroll
        for (int o = 32; o > 0; o >>= 1) S += __shfl_xor(S, o);
        float off2 = 0.0f;

        for (int m = 1; m < 64; ++m) {
            const int pidx = ((lane ^ m) << 2);
            // fetch partner column ONCE; q0..q63 stay live through rotation
#define FETCH(i) q##i = __int_as_float(__builtin_amdgcn_ds_bpermute(pidx, __float_as_int(w##i)));
            REP64(FETCH)
            // Gram cross-dot: 8 static-indexed partials (short dep chains)
            float gp[8] = {0.f, 0.f, 0.f, 0.f, 0.f, 0.f, 0.f, 0.f};
#define ACCG(i) gp[(i) & 7] = fmaf(w##i, q##i, gp[(i) & 7]);
            REP64(ACCG)
            const float g = ((gp[0] + gp[1]) + (gp[2] + gp[3])) +
                            ((gp[4] + gp[5]) + (gp[6] + gp[7]));
            off2 = fmaf(g, g, off2);
            const float nq = __int_as_float(__builtin_amdgcn_ds_bpermute(pidx, __float_as_int(n)));
            const bool isp = lane < (lane ^ m);
            const float na = isp ? n : nq;
            const float nb = isp ? nq : n;
            const float tau = (nb - na) * (0.5f * __builtin_amdgcn_rcpf(g));
            const float at  = fabsf(tau);
            float t = __builtin_amdgcn_rcpf(at + __builtin_amdgcn_sqrtf(fmaf(at, at, 1.0f)));
            t = copysignf(t, tau);
            float c = __builtin_amdgcn_rsqf(fmaf(t, t, 1.0f));
            float s = t * c;
            const bool tiny = !(fabsf(g) > 1e-28f);   // exact-0 / NaN guard
            c = tiny ? 1.0f : c;
            s = tiny ? 0.0f : s;
            const float tg = tiny ? 0.0f : t * g;
            const float se = isp ? -s : s;
#define ROT(i) w##i = fmaf(se, q##i, c * w##i);
            REP64(ROT)
            n += isp ? -tg : tg;
        }
#pragma unroll
        for (int o = 32; o > 0; o >>= 1) off2 += __shfl_xor(off2, o);
        if (sweep >= MIN_SWEEPS - 1 && off2 < 1e-13f * S * S) break;
    }

    // ---------------- epilogue (single pass, full wave) ----------------
    n = 0.0f;
    REP64(ACCN)
    const float rn = __builtin_amdgcn_rsqf(n);
#define NRM(i) w##i *= rn;
    REP64(NRM)

    // dump v (my eigenvector) to row `lane`
#define DUMP(i) vlds[lane * EP + (i)] = w##i;
    REP64(DUMP)
    __syncthreads();

    // fp64 Rayleigh vs ORIGINAL A: lambda = v^T A v (||v||=1);
    // inner dot in 4 static-indexed f64 partials
    double acc = 0.0;
    for (int r = 0; r < 64; ++r) {
        double ip[4] = {0.0, 0.0, 0.0, 0.0};
#define RAYI(i) ip[(i) >> 4] = fma((double)xm[r * 64 + (i)], (double)w##i, ip[(i) >> 4]);
        REP64(RAYI)
        const double inner = (ip[0] + ip[1]) + (ip[2] + ip[3]);
        acc = fma((double)vlds[lane * EP + r], inner, acc);
    }
    double lam = fmin(fmax(acc, (double)EPSV), (double)MAXEIG);
    const float f = (float)log(lam);

    // q_j <- f_j * v_j[lane]  (transpose read (4j+lane)%32: conflict-free)
#define G2(i) q##i = __uint_as_float(__builtin_amdgcn_readlane(__float_as_uint(f), (i))) * vlds[(i) * EP + lane];
    REP64(G2)

    // reconstruct 4 output rows at a time: Out[r][lane] = sum_j v_j[r]*q_j;
    // v_j[4rg..4rg+3] read as ONE float4 broadcast (rows 16B-aligned at EP=68)
    for (int rg = 0; rg < 16; ++rg) {
        const int rg4 = rg * 4;
        float a0 = 0.0f, a1 = 0.0f, a2 = 0.0f, a3 = 0.0f;
#define RECI(i) { const float4 vv = *(const float4*)(vlds + (i) * EP + rg4); \
                  a0 = fmaf(vv.x, q##i, a0); a1 = fmaf(vv.y, q##i, a1);      \
                  a2 = fmaf(vv.z, q##i, a2); a3 = fmaf(vv.w, q##i, a3); }
        REP64(RECI)
        om[(rg4 + 0) * 64 + lane] = a0;
        om[(rg4 + 1) * 64 + lane] = a1;
        om[(rg4 + 2) * 64 + lane] = a2;
        om[(rg4 + 3) * 64 + lane] = a3;
    }
}

extern "C" void kernel_launch(void* const* d_in, const int* in_sizes, int n_in,
                              void* d_out, int out_size, void* d_ws, size_t ws_size,
                              hipStream_t stream) {
    const float* x = (const float*)d_in[0];
    float* out = (float*)d_out;
    const int nmat = in_sizes[0] / 4096;
    spd_log_kernel<<<dim3(nmat), dim3(64), 0, stream>>>(x, out);
}

// Round 17
// 1666.893 us; speedup vs baseline: 1.4287x; 1.0258x over previous
//
#include <hip/hip_runtime.h>
#include <math.h>

#define MIN_SWEEPS 6
#define MAX_SWEEPS 9
#define EPSV 1e-3
#define MAXEIG 1000.0
#define EP 68   // epilogue LDS pitch: rows 16B-aligned (float4 broadcast reads);
                // transpose read (4i+lane)%32 conflict-free

// ONE 64-lane wave per 64x64 symmetric matrix. ONE-SIDED Jacobi in registers.
// B = A + 0.5*||A||_F*I (PSD for this data class); lane j owns column w_j as
// 64 NAMED registers; XOR tournament (partner lane^m); both partners compute
// bitwise-identical (c,s), so there is no broadcast step and no barrier.
//
// r14/r16 lesson: builtin ds_bpermute is rematerializable -> the compiler
// re-issued all 64 fetches for the rotation (129 LDS ops/round, VGPR 84).
// r17: fetches are ASM VOLATILE ds_bpermute_b32 (cannot be duplicated), one
// explicit s_waitcnt lgkmcnt(0) + sched_barrier(0) fence (guide rule #18:
// without the sched_barrier the compiler may hoist register-only consumers
// above the waitcnt). 65 LDS ops/round = the information floor.

#define REP64(X) \
  X(0) X(1) X(2) X(3) X(4) X(5) X(6) X(7) \
  X(8) X(9) X(10) X(11) X(12) X(13) X(14) X(15) \
  X(16) X(17) X(18) X(19) X(20) X(21) X(22) X(23) \
  X(24) X(25) X(26) X(27) X(28) X(29) X(30) X(31) \
  X(32) X(33) X(34) X(35) X(36) X(37) X(38) X(39) \
  X(40) X(41) X(42) X(43) X(44) X(45) X(46) X(47) \
  X(48) X(49) X(50) X(51) X(52) X(53) X(54) X(55) \
  X(56) X(57) X(58) X(59) X(60) X(61) X(62) X(63)

__global__ __launch_bounds__(64, 2)
void spd_log_kernel(const float* __restrict__ x, float* __restrict__ out) {
    __shared__ float vlds[64 * EP];   // 17.4 KB, epilogue only

    const int lane = (int)threadIdx.x;
    const size_t mat = blockIdx.x;
    const float* __restrict__ xm = x + mat * (size_t)4096;
    float* __restrict__ om = out + mat * (size_t)4096;

#define DECLW(i) float w##i;
    REP64(DECLW)
#define DECLQ(i) float q##i;
    REP64(DECLQ)

    // load my column of A
#define LOADW(i) w##i = xm[(i) * 64 + lane];
    REP64(LOADW)

    // gamma = 0.5 * ||A||_F
    float ff = 0.0f;
#define ACCF(i) ff = fmaf(w##i, w##i, ff);
    REP64(ACCF)
#pragma unroll
    for (int o = 32; o > 0; o >>= 1) ff += __shfl_xor(ff, o);
    const float gamma = 0.5f * sqrtf(ff);

    // B = A + gamma*I
#define SHIFTW(i) w##i += ((i) == lane) ? gamma : 0.0f;
    REP64(SHIFTW)

    float n = 0.0f;
#define ACCN(i) n = fmaf(w##i, w##i, n);
    REP64(ACCN)

    // ---------------- one-sided Jacobi sweeps (no barriers) ----------------
    for (int sweep = 0; sweep < MAX_SWEEPS; ++sweep) {
        n = 0.0f;                      // fresh norm kills recurrence drift
        REP64(ACCN)
        float S = n;
#pragma unroll
        for (int o = 32; o > 0; o >>= 1) S += __shfl_xor(S, o);
        float off2 = 0.0f;

        for (int m = 1; m < 64; ++m) {
            const int pidx = ((lane ^ m) << 2);
            // partner norm + partner column: volatile (non-rematerializable),
            // issued back-to-back; HW throttles at lgkmcnt depth.
            float nq;
            asm volatile("ds_bpermute_b32 %0, %1, %2"
                         : "=v"(nq) : "v"(pidx), "v"(n));
#define FETCH(i) asm volatile("ds_bpermute_b32 %0, %1, %2" \
                              : "=v"(q##i) : "v"(pidx), "v"(w##i));
            REP64(FETCH)
            asm volatile("s_waitcnt lgkmcnt(0)");
            __builtin_amdgcn_sched_barrier(0);

            // Gram cross-dot: 8 static-indexed partials (short dep chains)
            float gp[8] = {0.f, 0.f, 0.f, 0.f, 0.f, 0.f, 0.f, 0.f};
#define ACCG(i) gp[(i) & 7] = fmaf(w##i, q##i, gp[(i) & 7]);
            REP64(ACCG)
            const float g = ((gp[0] + gp[1]) + (gp[2] + gp[3])) +
                            ((gp[4] + gp[5]) + (gp[6] + gp[7]));
            off2 = fmaf(g, g, off2);
            const bool isp = lane < (lane ^ m);
            const float na = isp ? n : nq;
            const float nb = isp ? nq : n;
            const float tau = (nb - na) * (0.5f * __builtin_amdgcn_rcpf(g));
            const float at  = fabsf(tau);
            float t = __builtin_amdgcn_rcpf(at + __builtin_amdgcn_sqrtf(fmaf(at, at, 1.0f)));
            t = copysignf(t, tau);
            float c = __builtin_amdgcn_rsqf(fmaf(t, t, 1.0f));
            float s = t * c;
            const bool tiny = !(fabsf(g) > 1e-28f);   // exact-0 / NaN guard
            c = tiny ? 1.0f : c;
            s = tiny ? 0.0f : s;
            const float tg = tiny ? 0.0f : t * g;
            const float se = isp ? -s : s;
#define ROT(i) w##i = fmaf(se, q##i, c * w##i);
            REP64(ROT)
            n += isp ? -tg : tg;
        }
#pragma unroll
        for (int o = 32; o > 0; o >>= 1) off2 += __shfl_xor(off2, o);
        if (sweep >= MIN_SWEEPS - 1 && off2 < 1e-13f * S * S) break;
    }

    // ---------------- epilogue (single pass, full wave) ----------------
    n = 0.0f;
    REP64(ACCN)
    const float rn = __builtin_amdgcn_rsqf(n);
#define NRM(i) w##i *= rn;
    REP64(NRM)

    // dump v (my eigenvector) to row `lane`
#define DUMP(i) vlds[lane * EP + (i)] = w##i;
    REP64(DUMP)
    __syncthreads();

    // fp64 Rayleigh vs ORIGINAL A: lambda = v^T A v (||v||=1);
    // inner dot in 4 static-indexed f64 partials
    double acc = 0.0;
    for (int r = 0; r < 64; ++r) {
        double ip[4] = {0.0, 0.0, 0.0, 0.0};
#define RAYI(i) ip[(i) >> 4] = fma((double)xm[r * 64 + (i)], (double)w##i, ip[(i) >> 4]);
        REP64(RAYI)
        const double inner = (ip[0] + ip[1]) + (ip[2] + ip[3]);
        acc = fma((double)vlds[lane * EP + r], inner, acc);
    }
    double lam = fmin(fmax(acc, (double)EPSV), (double)MAXEIG);
    const float f = (float)log(lam);

    // q_j <- f_j * v_j[lane]  (transpose read (4j+lane)%32: conflict-free)
#define G2(i) q##i = __uint_as_float(__builtin_amdgcn_readlane(__float_as_uint(f), (i))) * vlds[(i) * EP + lane];
    REP64(G2)

    // reconstruct 4 output rows at a time: Out[r][lane] = sum_j v_j[r]*q_j;
    // v_j[4rg..4rg+3] read as ONE float4 broadcast (rows 16B-aligned at EP=68)
    for (int rg = 0; rg < 16; ++rg) {
        const int rg4 = rg * 4;
        float a0 = 0.0f, a1 = 0.0f, a2 = 0.0f, a3 = 0.0f;
#define RECI(i) { const float4 vv = *(const float4*)(vlds + (i) * EP + rg4); \
                  a0 = fmaf(vv.x, q##i, a0); a1 = fmaf(vv.y, q##i, a1);      \
                  a2 = fmaf(vv.z, q##i, a2); a3 = fmaf(vv.w, q##i, a3); }
        REP64(RECI)
        om[(rg4 + 0) * 64 + lane] = a0;
        om[(rg4 + 1) * 64 + lane] = a1;
        om[(rg4 + 2) * 64 + lane] = a2;
        om[(rg4 + 3) * 64 + lane] = a3;
    }
}

extern "C" void kernel_launch(void* const* d_in, const int* in_sizes, int n_in,
                              void* d_out, int out_size, void* d_ws, size_t ws_size,
                              hipStream_t stream) {
    const float* x = (const float*)d_in[0];
    float* out = (float*)d_out;
    const int nmat = in_sizes[0] / 4096;
    spd_log_kernel<<<dim3(nmat), dim3(64), 0, stream>>>(x, out);
}

// Round 19
// 1657.409 us; speedup vs baseline: 1.4369x; 1.0057x over previous
//
#include <hip/hip_runtime.h>
#include <math.h>

#define MIN_SWEEPS 6
#define MAX_SWEEPS 9
#define EPSV 1e-3
#define MAXEIG 1000.0
#define EP 68   // eigvec-major pitch: rows 16B-aligned (float4 broadcast reads)

// ONE 64-lane wave per 64x64 symmetric matrix. ONE-SIDED Jacobi in registers.
// B = A + 0.5*||A||_F*I (PSD for this data class); lane j owns column w_j as
// 64 NAMED registers; XOR tournament (partner lane^m) via volatile asm
// ds_bpermute (non-rematerializable) + lgkmcnt(0) + sched_barrier fence.
//
// r18 FAILED (NaN): __launch_bounds__(64,4) capped VGPR at 128 < the ~150
// this loop pins across the fetch block -> spill code interleaved between
// volatile ds_bpermutes reads asm output regs whose DS writes are still in
// flight (compiler waitcnt pass can't see pending ops inside asm). r19:
// restore the r17-proven (64,2) cap-256 allocation; keep r18's 8.7KB
// epilogue so occupancy is register-capped (~8-12 waves/CU), not LDS-capped
// (r17: 17.4KB -> 9 blocks/CU, 6.3 waves measured, both pipes ~50% idle).
//  - Rayleigh: two ELEMENT-major full-wave passes (no exec-masked heavy
//    compute -- r15's double-issue trap).
//  - Reconstruction: two EIGVEC-major passes; masked dump (cheap), full-wave
//    G2+FMA; pass 1 accumulates om +=.

#define REP64(X) \
  X(0) X(1) X(2) X(3) X(4) X(5) X(6) X(7) \
  X(8) X(9) X(10) X(11) X(12) X(13) X(14) X(15) \
  X(16) X(17) X(18) X(19) X(20) X(21) X(22) X(23) \
  X(24) X(25) X(26) X(27) X(28) X(29) X(30) X(31) \
  X(32) X(33) X(34) X(35) X(36) X(37) X(38) X(39) \
  X(40) X(41) X(42) X(43) X(44) X(45) X(46) X(47) \
  X(48) X(49) X(50) X(51) X(52) X(53) X(54) X(55) \
  X(56) X(57) X(58) X(59) X(60) X(61) X(62) X(63)

#define REP32(X) \
  X(0) X(1) X(2) X(3) X(4) X(5) X(6) X(7) \
  X(8) X(9) X(10) X(11) X(12) X(13) X(14) X(15) \
  X(16) X(17) X(18) X(19) X(20) X(21) X(22) X(23) \
  X(24) X(25) X(26) X(27) X(28) X(29) X(30) X(31)

__global__ __launch_bounds__(64, 2)
void spd_log_kernel(const float* __restrict__ x, float* __restrict__ out) {
    __shared__ float vlds[32 * EP];   // 8.7 KB; element-major uses 32*64 < 32*EP

    const int lane = (int)threadIdx.x;
    const int hb   = lane >> 5;       // my eigvec half (for recon dumps)
    const int rl   = lane & 31;       // my row within the half-buffer
    const size_t mat = blockIdx.x;
    const float* __restrict__ xm = x + mat * (size_t)4096;
    float* __restrict__ om = out + mat * (size_t)4096;

#define DECLW(i) float w##i;
    REP64(DECLW)
#define DECLQ(i) float q##i;
    REP64(DECLQ)

    // load my column of A
#define LOADW(i) w##i = xm[(i) * 64 + lane];
    REP64(LOADW)

    // gamma = 0.5 * ||A||_F
    float ff = 0.0f;
#define ACCF(i) ff = fmaf(w##i, w##i, ff);
    REP64(ACCF)
#pragma unroll
    for (int o = 32; o > 0; o >>= 1) ff += __shfl_xor(ff, o);
    const float gamma = 0.5f * sqrtf(ff);

    // B = A + gamma*I
#define SHIFTW(i) w##i += ((i) == lane) ? gamma : 0.0f;
    REP64(SHIFTW)

    float n = 0.0f;
#define ACCN(i) n = fmaf(w##i, w##i, n);
    REP64(ACCN)

    // ---------------- one-sided Jacobi sweeps (no barriers) ----------------
    for (int sweep = 0; sweep < MAX_SWEEPS; ++sweep) {
        n = 0.0f;                      // fresh norm kills recurrence drift
        REP64(ACCN)
        float S = n;
#pragma unroll
        for (int o = 32; o > 0; o >>= 1) S += __shfl_xor(S, o);
        float off2 = 0.0f;

        for (int m = 1; m < 64; ++m) {
            const int pidx = ((lane ^ m) << 2);
            float nq;
            asm volatile("ds_bpermute_b32 %0, %1, %2"
                         : "=v"(nq) : "v"(pidx), "v"(n));
#define FETCH(i) asm volatile("ds_bpermute_b32 %0, %1, %2" \
                              : "=v"(q##i) : "v"(pidx), "v"(w##i));
            REP64(FETCH)
            asm volatile("s_waitcnt lgkmcnt(0)");
            __builtin_amdgcn_sched_barrier(0);

            float gp[8] = {0.f, 0.f, 0.f, 0.f, 0.f, 0.f, 0.f, 0.f};
#define ACCG(i) gp[(i) & 7] = fmaf(w##i, q##i, gp[(i) & 7]);
            REP64(ACCG)
            const float g = ((gp[0] + gp[1]) + (gp[2] + gp[3])) +
                            ((gp[4] + gp[5]) + (gp[6] + gp[7]));
            off2 = fmaf(g, g, off2);
            const bool isp = lane < (lane ^ m);
            const float na = isp ? n : nq;
            const float nb = isp ? nq : n;
            const float tau = (nb - na) * (0.5f * __builtin_amdgcn_rcpf(g));
            const float at  = fabsf(tau);
            float t = __builtin_amdgcn_rcpf(at + __builtin_amdgcn_sqrtf(fmaf(at, at, 1.0f)));
            t = copysignf(t, tau);
            float c = __builtin_amdgcn_rsqf(fmaf(t, t, 1.0f));
            float s = t * c;
            const bool tiny = !(fabsf(g) > 1e-28f);   // exact-0 / NaN guard
            c = tiny ? 1.0f : c;
            s = tiny ? 0.0f : s;
            const float tg = tiny ? 0.0f : t * g;
            const float se = isp ? -s : s;
#define ROT(i) w##i = fmaf(se, q##i, c * w##i);
            REP64(ROT)
            n += isp ? -tg : tg;
        }
#pragma unroll
        for (int o = 32; o > 0; o >>= 1) off2 += __shfl_xor(off2, o);
        if (sweep >= MIN_SWEEPS - 1 && off2 < 1e-13f * S * S) break;
    }

    // ---------------- epilogue ----------------
    n = 0.0f;
    REP64(ACCN)
    const float rn = __builtin_amdgcn_rsqf(n);
#define NRM(i) w##i *= rn;
    REP64(NRM)

    // ---- fp64 Rayleigh vs ORIGINAL A in two element-major passes ----
    // pass A0: elements [0,32) of every column; stride-1 dump (free banks)
    double acc = 0.0;
#define DUMPA0(i) if ((i) < 32) vlds[(i) * 64 + lane] = w##i;
    REP64(DUMPA0)
    __syncthreads();
    for (int r = 0; r < 32; ++r) {
        double ip[4] = {0.0, 0.0, 0.0, 0.0};
#define RAYI(i) ip[(i) >> 4] = fma((double)xm[r * 64 + (i)], (double)w##i, ip[(i) >> 4]);
        REP64(RAYI)
        const double inner = (ip[0] + ip[1]) + (ip[2] + ip[3]);
        acc = fma((double)vlds[r * 64 + lane], inner, acc);
    }
    __syncthreads();
    // pass A1: elements [32,64)
#define DUMPA1(i) if ((i) >= 32) vlds[((i) - 32) * 64 + lane] = w##i;
    REP64(DUMPA1)
    __syncthreads();
    for (int r = 32; r < 64; ++r) {
        double ip[4] = {0.0, 0.0, 0.0, 0.0};
        REP64(RAYI)
        const double inner = (ip[0] + ip[1]) + (ip[2] + ip[3]);
        acc = fma((double)vlds[(r - 32) * 64 + lane], inner, acc);
    }

    double lam = fmin(fmax(acc, (double)EPSV), (double)MAXEIG);
    const float f = (float)log(lam);

    // ---- reconstruction in two eigvec-major passes over column halves ----
#pragma unroll
    for (int P = 0; P < 2; ++P) {
        __syncthreads();   // previous pass's readers done
        if (hb == P) {
            // dump my eigenvector into row rl
#define DUMPB(i) vlds[rl * EP + (i)] = w##i;
            REP64(DUMPB)
        }
        __syncthreads();

        // q_i <- f_j * v_j[lane] for j = 32P+i (row read, stride-1, free)
#define G2(i) q##i = __uint_as_float(__builtin_amdgcn_readlane(__float_as_uint(f), 32 * P + (i))) * vlds[(i) * EP + lane];
        REP32(G2)

        // Out[r][lane] (+)= sum_{i<32} v_j[r] * q_i ; rows 4 at a time via
        // float4 uniform broadcast (EP=68 keeps rows 16B-aligned)
        for (int rg = 0; rg < 16; ++rg) {
            const int rg4 = rg * 4;
            float a0 = 0.0f, a1 = 0.0f, a2 = 0.0f, a3 = 0.0f;
#define RECI(i) { const float4 vv = *(const float4*)(vlds + (i) * EP + rg4); \
                  a0 = fmaf(vv.x, q##i, a0); a1 = fmaf(vv.y, q##i, a1);      \
                  a2 = fmaf(vv.z, q##i, a2); a3 = fmaf(vv.w, q##i, a3); }
            REP32(RECI)
            if (P == 0) {
                om[(rg4 + 0) * 64 + lane] = a0;
                om[(rg4 + 1) * 64 + lane] = a1;
                om[(rg4 + 2) * 64 + lane] = a2;
                om[(rg4 + 3) * 64 + lane] = a3;
            } else {
                om[(rg4 + 0) * 64 + lane] += a0;
                om[(rg4 + 1) * 64 + lane] += a1;
                om[(rg4 + 2) * 64 + lane] += a2;
                om[(rg4 + 3) * 64 + lane] += a3;
            }
        }
    }
}

extern "C" void kernel_launch(void* const* d_in, const int* in_sizes, int n_in,
                              void* d_out, int out_size, void* d_ws, size_t ws_size,
                              hipStream_t stream) {
    const float* x = (const float*)d_in[0];
    float* out = (float*)d_out;
    const int nmat = in_sizes[0] / 4096;
    spd_log_kernel<<<dim3(nmat), dim3(64), 0, stream>>>(x, out);
}

// Round 20
// 1651.671 us; speedup vs baseline: 1.4419x; 1.0035x over previous
//
#include <hip/hip_runtime.h>
#include <math.h>

#define MIN_SWEEPS 6
#define MAX_SWEEPS 9
#define EPSV 1e-3
#define MAXEIG 1000.0
#define EP 68   // eigvec-major pitch: rows 16B-aligned (float4 broadcast reads)

// ONE 64-lane wave per 64x64 symmetric matrix. ONE-SIDED Jacobi in registers.
// B = A + 0.5*||A||_F*I (PSD for this data class); lane j owns column as
// NAMED registers; XOR tournament (partner lane^m) via volatile asm
// ds_bpermute + lgkmcnt(0) + sched_barrier fence.
//
// r19 model fit: SIMDs are ISSUE-SLOT saturated at ~2 waves/SIMD — wall ~
// (VALU_instr*2cyc + DS_ops*5.8cyc)/round; r14/16/17/19 all ~1.65ms because
// their issue totals match. r20 cuts the biggest VALU block with FAST-GIVENS
// scaled rotations: w_j = alpha_j * u_j;  u'_p = u_p - t*(aq/ap)*u_q,
// alpha'_p = c*alpha_p  -> ONE fma per element (was mul+fma). alpha folded
// into u at each sweep start. Bounds: c >= 0.707 per rotation -> alpha >=
// 2^-31.5 within a sweep, u <= 2^36, dot <= 2^78: all safe fp32. The final
// normalization v = u/||u|| cancels alpha, so the epilogue is unchanged.

#define REP64(X) \
  X(0) X(1) X(2) X(3) X(4) X(5) X(6) X(7) \
  X(8) X(9) X(10) X(11) X(12) X(13) X(14) X(15) \
  X(16) X(17) X(18) X(19) X(20) X(21) X(22) X(23) \
  X(24) X(25) X(26) X(27) X(28) X(29) X(30) X(31) \
  X(32) X(33) X(34) X(35) X(36) X(37) X(38) X(39) \
  X(40) X(41) X(42) X(43) X(44) X(45) X(46) X(47) \
  X(48) X(49) X(50) X(51) X(52) X(53) X(54) X(55) \
  X(56) X(57) X(58) X(59) X(60) X(61) X(62) X(63)

#define REP32(X) \
  X(0) X(1) X(2) X(3) X(4) X(5) X(6) X(7) \
  X(8) X(9) X(10) X(11) X(12) X(13) X(14) X(15) \
  X(16) X(17) X(18) X(19) X(20) X(21) X(22) X(23) \
  X(24) X(25) X(26) X(27) X(28) X(29) X(30) X(31)

__global__ __launch_bounds__(64, 2)
void spd_log_kernel(const float* __restrict__ x, float* __restrict__ out) {
    __shared__ float vlds[32 * EP];   // 8.7 KB; element-major uses 32*64 < 32*EP

    const int lane = (int)threadIdx.x;
    const int hb   = lane >> 5;       // my eigvec half (for recon dumps)
    const int rl   = lane & 31;       // my row within the half-buffer
    const size_t mat = blockIdx.x;
    const float* __restrict__ xm = x + mat * (size_t)4096;
    float* __restrict__ om = out + mat * (size_t)4096;

#define DECLW(i) float w##i;
    REP64(DECLW)
#define DECLQ(i) float q##i;
    REP64(DECLQ)

    // load my column of A
#define LOADW(i) w##i = xm[(i) * 64 + lane];
    REP64(LOADW)

    // gamma = 0.5 * ||A||_F
    float ff = 0.0f;
#define ACCF(i) ff = fmaf(w##i, w##i, ff);
    REP64(ACCF)
#pragma unroll
    for (int o = 32; o > 0; o >>= 1) ff += __shfl_xor(ff, o);
    const float gamma = 0.5f * sqrtf(ff);

    // B = A + gamma*I
#define SHIFTW(i) w##i += ((i) == lane) ? gamma : 0.0f;
    REP64(SHIFTW)

    float av = 1.0f;   // alpha: true column = av * w
    float n = 0.0f;    // TRUE squared norm of the column
#define ACCN(i) n = fmaf(w##i, w##i, n);
    REP64(ACCN)

    // ---------------- one-sided Jacobi sweeps (no barriers) ----------------
    for (int sweep = 0; sweep < MAX_SWEEPS; ++sweep) {
        // fold alpha into the column; recompute true norm (kills drift)
#define FOLD(i) w##i *= av;
        REP64(FOLD)
        av = 1.0f;
        n = 0.0f;
        REP64(ACCN)
        float S = n;
#pragma unroll
        for (int o = 32; o > 0; o >>= 1) S += __shfl_xor(S, o);
        float off2 = 0.0f;

        for (int m = 1; m < 64; ++m) {
            const int pidx = ((lane ^ m) << 2);
            float nq, bv;
            asm volatile("ds_bpermute_b32 %0, %1, %2"
                         : "=v"(nq) : "v"(pidx), "v"(n));
            asm volatile("ds_bpermute_b32 %0, %1, %2"
                         : "=v"(bv) : "v"(pidx), "v"(av));
#define FETCH(i) asm volatile("ds_bpermute_b32 %0, %1, %2" \
                              : "=v"(q##i) : "v"(pidx), "v"(w##i));
            REP64(FETCH)
            asm volatile("s_waitcnt lgkmcnt(0)");
            __builtin_amdgcn_sched_barrier(0);

            // scaled Gram cross-dot; g in TRUE units
            float gp[8] = {0.f, 0.f, 0.f, 0.f, 0.f, 0.f, 0.f, 0.f};
#define ACCG(i) gp[(i) & 7] = fmaf(w##i, q##i, gp[(i) & 7]);
            REP64(ACCG)
            const float gu = ((gp[0] + gp[1]) + (gp[2] + gp[3])) +
                             ((gp[4] + gp[5]) + (gp[6] + gp[7]));
            const float g = (av * bv) * gu;
            off2 = fmaf(g, g, off2);
            const bool isp = lane < (lane ^ m);
            const float na = isp ? n : nq;
            const float nb = isp ? nq : n;
            const float tau = (nb - na) * (0.5f * __builtin_amdgcn_rcpf(g));
            const float at  = fabsf(tau);
            float t = __builtin_amdgcn_rcpf(at + __builtin_amdgcn_sqrtf(fmaf(at, at, 1.0f)));
            t = copysignf(t, tau);
            const float cc = __builtin_amdgcn_rsqf(fmaf(t, t, 1.0f));
            const bool tiny = !(fabsf(g) > 1e-28f);   // exact-0 / NaN guard
            // fast-Givens: u' = u + rfac*q with rfac = -/+ t*(alpha_other/alpha_mine)
            float rfac = t * (bv * __builtin_amdgcn_rcpf(av));
            rfac = isp ? -rfac : rfac;
            rfac = tiny ? 0.0f : rfac;
            const float cf = tiny ? 1.0f : cc;
            const float tg = tiny ? 0.0f : t * g;
#define ROT(i) w##i = fmaf(rfac, q##i, w##i);
            REP64(ROT)
            av *= cf;
            n += isp ? -tg : tg;
        }
#pragma unroll
        for (int o = 32; o > 0; o >>= 1) off2 += __shfl_xor(off2, o);
        if (sweep >= MIN_SWEEPS - 1 && off2 < 1e-13f * S * S) break;
    }

    // ---------------- epilogue (alpha cancels in normalization) ------------
    n = 0.0f;
    REP64(ACCN)
    const float rn = __builtin_amdgcn_rsqf(n);
#define NRM(i) w##i *= rn;
    REP64(NRM)

    // ---- fp64 Rayleigh vs ORIGINAL A in two element-major passes ----
    double acc = 0.0;
#define DUMPA0(i) if ((i) < 32) vlds[(i) * 64 + lane] = w##i;
    REP64(DUMPA0)
    __syncthreads();
    for (int r = 0; r < 32; ++r) {
        double ip[4] = {0.0, 0.0, 0.0, 0.0};
#define RAYI(i) ip[(i) >> 4] = fma((double)xm[r * 64 + (i)], (double)w##i, ip[(i) >> 4]);
        REP64(RAYI)
        const double inner = (ip[0] + ip[1]) + (ip[2] + ip[3]);
        acc = fma((double)vlds[r * 64 + lane], inner, acc);
    }
    __syncthreads();
#define DUMPA1(i) if ((i) >= 32) vlds[((i) - 32) * 64 + lane] = w##i;
    REP64(DUMPA1)
    __syncthreads();
    for (int r = 32; r < 64; ++r) {
        double ip[4] = {0.0, 0.0, 0.0, 0.0};
        REP64(RAYI)
        const double inner = (ip[0] + ip[1]) + (ip[2] + ip[3]);
        acc = fma((double)vlds[(r - 32) * 64 + lane], inner, acc);
    }

    double lam = fmin(fmax(acc, (double)EPSV), (double)MAXEIG);
    const float f = (float)log(lam);

    // ---- reconstruction in two eigvec-major passes over column halves ----
#pragma unroll
    for (int P = 0; P < 2; ++P) {
        __syncthreads();   // previous pass's readers done
        if (hb == P) {
#define DUMPB(i) vlds[rl * EP + (i)] = w##i;
            REP64(DUMPB)
        }
        __syncthreads();

        // q_i <- f_j * v_j[lane] for j = 32P+i (row read, stride-1, free)
#define G2(i) q##i = __uint_as_float(__builtin_amdgcn_readlane(__float_as_uint(f), 32 * P + (i))) * vlds[(i) * EP + lane];
        REP32(G2)

        // Out[r][lane] (+)= sum_{i<32} v_j[r] * q_i ; rows 4 at a time via
        // float4 uniform broadcast (EP=68 keeps rows 16B-aligned)
        for (int rg = 0; rg < 16; ++rg) {
            const int rg4 = rg * 4;
            float a0 = 0.0f, a1 = 0.0f, a2 = 0.0f, a3 = 0.0f;
#define RECI(i) { const float4 vv = *(const float4*)(vlds + (i) * EP + rg4); \
                  a0 = fmaf(vv.x, q##i, a0); a1 = fmaf(vv.y, q##i, a1);      \
                  a2 = fmaf(vv.z, q##i, a2); a3 = fmaf(vv.w, q##i, a3); }
            REP32(RECI)
            if (P == 0) {
                om[(rg4 + 0) * 64 + lane] = a0;
                om[(rg4 + 1) * 64 + lane] = a1;
                om[(rg4 + 2) * 64 + lane] = a2;
                om[(rg4 + 3) * 64 + lane] = a3;
            } else {
                om[(rg4 + 0) * 64 + lane] += a0;
                om[(rg4 + 1) * 64 + lane] += a1;
                om[(rg4 + 2) * 64 + lane] += a2;
                om[(rg4 + 3) * 64 + lane] += a3;
            }
        }
    }
}

extern "C" void kernel_launch(void* const* d_in, const int* in_sizes, int n_in,
                              void* d_out, int out_size, void* d_ws, size_t ws_size,
                              hipStream_t stream) {
    const float* x = (const float*)d_in[0];
    float* out = (float*)d_out;
    const int nmat = in_sizes[0] / 4096;
    spd_log_kernel<<<dim3(nmat), dim3(64), 0, stream>>>(x, out);
}